// Round 21
// baseline (536.610 us; speedup 1.0000x reference)
//
#include <hip/hip_runtime.h>

typedef __bf16 bf16;
typedef __bf16 bf16x8 __attribute__((ext_vector_type(8)));
typedef float f32x4 __attribute__((ext_vector_type(4)));

#define S_NB 50

// ---------------- weight pre-shuffle: f32 -> bf16 MFMA B-fragment layout ----
__global__ __launch_bounds__(256) void shuffle_w(const float* __restrict__ gatW,
                                                 bf16* __restrict__ ws) {
  int tid = blockIdx.x * 256 + threadIdx.x;
  if (tid >= 6 * 512) return;
  int mat = tid >> 9;
  int rem = tid & 511;
  int ks = rem >> 8;
  int nt = (rem >> 6) & 3;
  int lane = rem & 63;
  int t = mat >> 1, p = (mat & 1) + 1;
  const float* src = gatW + (size_t)(t * 4 + p) * 4096;
  int n = nt * 16 + (lane & 15);
  int kb = ks * 32 + (lane >> 4) * 8;
  bf16x8 v;
#pragma unroll
  for (int e = 0; e < 8; ++e) v[e] = (bf16)src[(kb + e) * 64 + n];
  *reinterpret_cast<bf16x8*>(ws + mat * 4096 + ((ks * 4 + nt) * 64 + lane) * 8) = v;
}

// inst mapping: 0:U(u_movies,item | node user[uids])  1:M(m_querys,query | item[mids])
//               2:M(m_users,user | item[mids])        3:Q(q_movies,item | query[qids])

// ---- gat_all: qp + scores + softmax + PV + agg, one wave per (inst, b). ----
// W0/W3 staged in LDS once per block (blocks are inst-uniform): the qp/agg
// 64-load chains hit LDS (~60cy) instead of L2 (~200cy). Math bit-identical.
__global__ __launch_bounds__(256) void gat_all(
    const int* __restrict__ uids, const int* __restrict__ qids,
    const int* __restrict__ mids, const int* __restrict__ u_movies,
    const int* __restrict__ m_querys, const int* __restrict__ m_users,
    const int* __restrict__ q_movies, const float* __restrict__ user_t,
    const float* __restrict__ item_t, const float* __restrict__ query_t,
    const float* __restrict__ gatW, const float* __restrict__ gatB,
    const bf16* __restrict__ wfrag, float* __restrict__ agg, int B) {
  __shared__ float ldsW[8192];  // [0,4096) = W0, [4096,8192) = W3

  int ib = (blockIdx.x * 256 + threadIdx.x) >> 6;
  int lane = threadIdx.x & 63;
  int tid = threadIdx.x;
  int inst = ib / B;
  int b = ib - inst * B;
  int c15 = lane & 15, g = lane >> 4;

  const int* idx; const float* nbt; const float* ndt; int ndid; int woff;
  if (inst == 0) { idx = u_movies; nbt = item_t; ndt = user_t; ndid = uids[b]; woff = 0; }
  else if (inst == 1) { idx = m_querys; nbt = query_t; ndt = item_t; ndid = mids[b]; woff = 1; }
  else if (inst == 2) { idx = m_users; nbt = user_t; ndt = item_t; ndid = mids[b]; woff = 1; }
  else { idx = q_movies; nbt = item_t; ndt = query_t; ndid = qids[b]; woff = 2; }
  const float* Wt = gatW + (size_t)woff * 4 * 4096;
  const float* bt = gatB + woff * 256;
  const bf16* frk = wfrag + woff * 8192;        // K frags
  const bf16* frv = wfrag + woff * 8192 + 4096; // V frags

  // cooperative LDS stage of W0 and W3 (inst is block-uniform: B % 4 == 0)
  {
    const float4* w0v = reinterpret_cast<const float4*>(Wt);
    const float4* w3v = reinterpret_cast<const float4*>(Wt + 3 * 4096);
    float4* l0 = reinterpret_cast<float4*>(ldsW);
    float4* l3 = reinterpret_cast<float4*>(ldsW + 4096);
#pragma unroll
    for (int i = 0; i < 4; ++i) {
      l0[tid + i * 256] = w0v[tid + i * 256];
      l3[tid + i * 256] = w3v[tid + i * 256];
    }
  }

  // node row (one 256B gather per wave)
  float nd = ndt[(size_t)ndid * 64 + lane];

  // A fragments for all 4 m-tiles (rows 50..63 -> id 0 = zero row)
  bf16x8 af0[4], af1[4];
#pragma unroll
  for (int m = 0; m < 4; ++m) {
    int arow = m * 16 + c15;
    int id = (arow < S_NB) ? idx[b * S_NB + arow] : 0;
    const float* rowp = nbt + (size_t)id * 64;
    float4 f0 = *reinterpret_cast<const float4*>(rowp + g * 8);
    float4 f1 = *reinterpret_cast<const float4*>(rowp + g * 8 + 4);
    float4 f2 = *reinterpret_cast<const float4*>(rowp + 32 + g * 8);
    float4 f3 = *reinterpret_cast<const float4*>(rowp + 32 + g * 8 + 4);
    af0[m][0] = (bf16)f0.x; af0[m][1] = (bf16)f0.y; af0[m][2] = (bf16)f0.z; af0[m][3] = (bf16)f0.w;
    af0[m][4] = (bf16)f1.x; af0[m][5] = (bf16)f1.y; af0[m][6] = (bf16)f1.z; af0[m][7] = (bf16)f1.w;
    af1[m][0] = (bf16)f2.x; af1[m][1] = (bf16)f2.y; af1[m][2] = (bf16)f2.z; af1[m][3] = (bf16)f2.w;
    af1[m][4] = (bf16)f3.x; af1[m][5] = (bf16)f3.y; af1[m][6] = (bf16)f3.z; af1[m][7] = (bf16)f3.w;
  }

  __syncthreads();  // LDS weights ready (single barrier per block lifetime)

  // qp[col=lane] = relu(node @ W0 + b0), weights from LDS (same order as r17)
  float qv_own;
  {
    float q0 = 0.f, q1 = 0.f, q2 = 0.f, q3 = 0.f;
#pragma unroll 4
    for (int k = 0; k < 64; k += 4) {
      q0 += __shfl(nd, k, 64) * ldsW[k * 64 + lane];
      q1 += __shfl(nd, k + 1, 64) * ldsW[(k + 1) * 64 + lane];
      q2 += __shfl(nd, k + 2, 64) * ldsW[(k + 2) * 64 + lane];
      q3 += __shfl(nd, k + 3, 64) * ldsW[(k + 3) * 64 + lane];
    }
    qv_own = fmaxf((((q0 + q1) + q2) + q3) + bt[lane], 0.f);
  }

  // K phase: scores s[m][e] (row = m*16 + g*4 + e, summed over nt cols)
  float s[4][4];
#pragma unroll
  for (int m = 0; m < 4; ++m)
#pragma unroll
    for (int e = 0; e < 4; ++e) s[m][e] = 0.f;
#pragma unroll
  for (int nt = 0; nt < 4; ++nt) {
    bf16x8 bk0 = *reinterpret_cast<const bf16x8*>(frk + ((0 * 4 + nt) * 64 + lane) * 8);
    bf16x8 bk1 = *reinterpret_cast<const bf16x8*>(frk + ((1 * 4 + nt) * 64 + lane) * 8);
    float kb = bt[64 + nt * 16 + c15];
    float qpv = __shfl(qv_own, nt * 16 + c15, 64);
#pragma unroll
    for (int m = 0; m < 4; ++m) {
      f32x4 acc = {0.f, 0.f, 0.f, 0.f};
      acc = __builtin_amdgcn_mfma_f32_16x16x32_bf16(af0[m], bk0, acc, 0, 0, 0);
      acc = __builtin_amdgcn_mfma_f32_16x16x32_bf16(af1[m], bk1, acc, 0, 0, 0);
#pragma unroll
      for (int e = 0; e < 4; ++e) s[m][e] += fmaxf(acc[e] + kb, 0.f) * qpv;
    }
  }
#pragma unroll
  for (int msk = 1; msk < 16; msk <<= 1)
#pragma unroll
    for (int m = 0; m < 4; ++m)
#pragma unroll
      for (int e = 0; e < 4; ++e) s[m][e] += __shfl_xor(s[m][e], msk, 64);

  // transpose to per-lane score: lane wants row == lane
  int m_l = lane >> 4, e_l = lane & 3, gg = (lane & 15) >> 2;
  float sv = -1e30f;
#pragma unroll
  for (int m = 0; m < 4; ++m)
#pragma unroll
    for (int e = 0; e < 4; ++e) {
      float v = __shfl(s[m][e], gg * 16, 64);
      sv = (m_l == m && e_l == e) ? v : sv;
    }

  // softmax over 50 (scale 1/8 folded into exp), in-wave
  float svm = (lane < S_NB) ? sv : -1e30f;
  float mx = svm;
#pragma unroll
  for (int msk = 1; msk < 64; msk <<= 1) mx = fmaxf(mx, __shfl_xor(mx, msk, 64));
  float ev = (lane < S_NB) ? __expf((svm - mx) * 0.125f) : 0.f;
  float den = ev;
#pragma unroll
  for (int msk = 1; msk < 64; msk <<= 1) den += __shfl_xor(den, msk, 64);
  float pv = ev / den;

  // prob weights for PV: pw[m][e] = prob of row m*16 + g*4 + e
  float pwv[4][4];
#pragma unroll
  for (int m = 0; m < 4; ++m)
#pragma unroll
    for (int e = 0; e < 4; ++e) pwv[m][e] = __shfl(pv, m * 16 + g * 4 + e, 64);

  // V phase: PV accumulate (A-frags reused from registers)
  float yacc[4] = {0.f, 0.f, 0.f, 0.f};
#pragma unroll
  for (int nt = 0; nt < 4; ++nt) {
    bf16x8 bv0 = *reinterpret_cast<const bf16x8*>(frv + ((0 * 4 + nt) * 64 + lane) * 8);
    bf16x8 bv1 = *reinterpret_cast<const bf16x8*>(frv + ((1 * 4 + nt) * 64 + lane) * 8);
    float vb = bt[128 + nt * 16 + c15];
#pragma unroll
    for (int m = 0; m < 4; ++m) {
      f32x4 acc = {0.f, 0.f, 0.f, 0.f};
      acc = __builtin_amdgcn_mfma_f32_16x16x32_bf16(af0[m], bv0, acc, 0, 0, 0);
      acc = __builtin_amdgcn_mfma_f32_16x16x32_bf16(af1[m], bv1, acc, 0, 0, 0);
      yacc[nt] += pwv[m][0] * fmaxf(acc[0] + vb, 0.f) +
                  pwv[m][1] * fmaxf(acc[1] + vb, 0.f) +
                  pwv[m][2] * fmaxf(acc[2] + vb, 0.f) +
                  pwv[m][3] * fmaxf(acc[3] + vb, 0.f);
    }
  }
#pragma unroll
  for (int nt = 0; nt < 4; ++nt) {
    yacc[nt] += __shfl_xor(yacc[nt], 16, 64);
    yacc[nt] += __shfl_xor(yacc[nt], 32, 64);
  }
  // after xor 16/32, lane l holds yacc[nt] = y[nt*16 + (l&15)] for every l.

  // agg = relu(y @ W3 + b3), W3 from LDS (same 4-acc order as r17)
  {
    float a0 = 0.f, a1 = 0.f, a2 = 0.f, a3 = 0.f;
#pragma unroll
    for (int k = 0; k < 64; k += 4) {
      a0 += __shfl(yacc[(k + 0) >> 4], (k + 0) & 15, 64) * ldsW[4096 + (k + 0) * 64 + lane];
      a1 += __shfl(yacc[(k + 1) >> 4], (k + 1) & 15, 64) * ldsW[4096 + (k + 1) * 64 + lane];
      a2 += __shfl(yacc[(k + 2) >> 4], (k + 2) & 15, 64) * ldsW[4096 + (k + 2) * 64 + lane];
      a3 += __shfl(yacc[(k + 3) >> 4], (k + 3) & 15, 64) * ldsW[4096 + (k + 3) * 64 + lane];
    }
    agg[(size_t)ib * 64 + lane] =
        fmaxf((((a0 + a1) + a2) + a3) + gatB[woff * 256 + 192 + lane], 0.f);
  }
}

// ---- k_sem: semantic attention. one wave per (tower, b). -------------------
// W1/W2 staged in LDS once per block (blocks are tower-uniform).
__global__ __launch_bounds__(256) void k_sem(
    const int* __restrict__ uids, const int* __restrict__ qids,
    const int* __restrict__ mids, const float* __restrict__ user_t,
    const float* __restrict__ item_t, const float* __restrict__ query_t,
    const float* __restrict__ semW, const float* __restrict__ semB,
    const float* __restrict__ agg, float* __restrict__ out, int B) {
  __shared__ float ldsKV[8192];  // [0,4096) = W1, [4096,8192) = W2

  int w = (blockIdx.x * 256 + threadIdx.x) >> 6;
  int lane = threadIdx.x & 63;
  int tid = threadIdx.x;
  int t = w / B;
  int b = w - t * B;

  const float* Ws = semW + (size_t)t * 4 * 4096;
  const float* bs = semB + t * 256;

  // cooperative LDS stage of W1, W2 (t is block-uniform: B % 4 == 0)
  {
    const float4* w1v = reinterpret_cast<const float4*>(Ws + 4096);
    const float4* w2v = reinterpret_cast<const float4*>(Ws + 2 * 4096);
    float4* l1 = reinterpret_cast<float4*>(ldsKV);
    float4* l2 = reinterpret_cast<float4*>(ldsKV + 4096);
#pragma unroll
    for (int i = 0; i < 4; ++i) {
      l1[tid + i * 256] = w1v[tid + i * 256];
      l2[tid + i * 256] = w2v[tid + i * 256];
    }
  }

  float nd, k1v, k2v;
  int ns;
  if (t == 0) {
    nd = user_t[(size_t)uids[b] * 64 + lane];
    k1v = agg[(size_t)(0 * B + b) * 64 + lane];
    k2v = k1v; ns = 2;
  } else if (t == 1) {
    nd = item_t[(size_t)mids[b] * 64 + lane];
    k1v = agg[(size_t)(1 * B + b) * 64 + lane];
    k2v = agg[(size_t)(2 * B + b) * 64 + lane];
    ns = 3;
  } else {
    nd = query_t[(size_t)qids[b] * 64 + lane];
    k1v = agg[(size_t)(3 * B + b) * 64 + lane];
    k2v = k1v; ns = 2;
  }

  __syncthreads();  // LDS weights ready

  // qs = relu(node @ W0 + b0), col = lane (W0 from L2 - off critical chain)
  float q0 = 0.f, q1 = 0.f;
#pragma unroll 4
  for (int k = 0; k < 64; k += 2) {
    q0 += __shfl(nd, k, 64) * Ws[k * 64 + lane];
    q1 += __shfl(nd, k + 1, 64) * Ws[(k + 1) * 64 + lane];
  }
  float qs = fmaxf(q0 + q1 + bs[lane], 0.f);

  // kp/vp rows for keys {node, k1, k2}; W1/W2 from LDS
  float kp0 = 0.f, kp1 = 0.f, kp2 = 0.f, vp0 = 0.f, vp1 = 0.f, vp2 = 0.f;
#pragma unroll 2
  for (int k = 0; k < 64; ++k) {
    float w1 = ldsKV[k * 64 + lane];
    float w2 = ldsKV[4096 + k * 64 + lane];
    float nk = __shfl(nd, k, 64);
    float a1k = __shfl(k1v, k, 64);
    float a2k = __shfl(k2v, k, 64);
    kp0 += nk * w1; kp1 += a1k * w1; kp2 += a2k * w1;
    vp0 += nk * w2; vp1 += a1k * w2; vp2 += a2k * w2;
  }
  float bk = bs[64 + lane], bv = bs[128 + lane];
  kp0 = fmaxf(kp0 + bk, 0.f); kp1 = fmaxf(kp1 + bk, 0.f); kp2 = fmaxf(kp2 + bk, 0.f);
  vp0 = fmaxf(vp0 + bv, 0.f); vp1 = fmaxf(vp1 + bv, 0.f); vp2 = fmaxf(vp2 + bv, 0.f);

  // scores = dot(qs, kp_r)/8 via xor-tree
  float s0 = qs * kp0, s1 = qs * kp1, s2 = qs * kp2;
#pragma unroll
  for (int msk = 1; msk < 64; msk <<= 1) {
    s0 += __shfl_xor(s0, msk, 64);
    s1 += __shfl_xor(s1, msk, 64);
    s2 += __shfl_xor(s2, msk, 64);
  }
  s0 *= 0.125f; s1 *= 0.125f; s2 *= 0.125f;
  float mx = fmaxf(s0, s1);
  if (ns > 2) mx = fmaxf(mx, s2);
  float e0 = __expf(s0 - mx);
  float e1 = __expf(s1 - mx);
  float e2 = (ns > 2) ? __expf(s2 - mx) : 0.f;
  float rd = 1.f / (e0 + e1 + e2);
  float yv = (e0 * vp0 + e1 * vp1 + e2 * vp2) * rd;

  // out = relu(y @ W3 + b3)
  const float* W3 = Ws + 3 * 4096;
  float o0 = 0.f, o1 = 0.f;
#pragma unroll 4
  for (int k = 0; k < 64; k += 2) {
    o0 += __shfl(yv, k, 64) * W3[k * 64 + lane];
    o1 += __shfl(yv, k + 1, 64) * W3[(k + 1) * 64 + lane];
  }
  out[(size_t)b * 192 + t * 64 + lane] = fmaxf(o0 + o1 + bs[192 + lane], 0.f);
}

extern "C" void kernel_launch(void* const* d_in, const int* in_sizes, int n_in,
                              void* d_out, int out_size, void* d_ws, size_t ws_size,
                              hipStream_t stream) {
  const int* uids = (const int*)d_in[0];
  const int* qids = (const int*)d_in[1];
  const int* mids = (const int*)d_in[2];
  const int* u_movies = (const int*)d_in[3];
  const int* m_querys = (const int*)d_in[4];
  const int* m_users = (const int*)d_in[5];
  const int* q_movies = (const int*)d_in[6];
  const float* user_t = (const float*)d_in[7];
  const float* item_t = (const float*)d_in[8];
  const float* query_t = (const float*)d_in[9];
  const float* gatW = (const float*)d_in[10];
  const float* gatB = (const float*)d_in[11];
  const float* semW = (const float*)d_in[12];
  const float* semB = (const float*)d_in[13];
  float* out = (float*)d_out;

  int B = in_sizes[0];
  bf16* wfrag = (bf16*)d_ws;
  float* wsf = (float*)d_ws;
  float* agg = wsf + 16384;  // 4*B*64 floats

  shuffle_w<<<12, 256, 0, stream>>>(gatW, wfrag);
  gat_all<<<B, 256, 0, stream>>>(uids, qids, mids, u_movies, m_querys,
                                 m_users, q_movies, user_t, item_t, query_t,
                                 gatW, gatB, wfrag, agg, B);
  k_sem<<<3 * B / 4, 256, 0, stream>>>(uids, qids, mids, user_t, item_t,
                                       query_t, semW, semB, agg, out, B);
}

// Round 22
// 526.686 us; speedup vs baseline: 1.0188x; 1.0188x over previous
//
#include <hip/hip_runtime.h>

typedef __bf16 bf16;
typedef __bf16 bf16x8 __attribute__((ext_vector_type(8)));
typedef float f32x4 __attribute__((ext_vector_type(4)));

#define S_NB 50

// ---------------- weight pre-shuffle: f32 -> bf16 MFMA B-fragment layout ----
__global__ __launch_bounds__(256) void shuffle_w(const float* __restrict__ gatW,
                                                 bf16* __restrict__ ws) {
  int tid = blockIdx.x * 256 + threadIdx.x;
  if (tid >= 6 * 512) return;
  int mat = tid >> 9;
  int rem = tid & 511;
  int ks = rem >> 8;
  int nt = (rem >> 6) & 3;
  int lane = rem & 63;
  int t = mat >> 1, p = (mat & 1) + 1;
  const float* src = gatW + (size_t)(t * 4 + p) * 4096;
  int n = nt * 16 + (lane & 15);
  int kb = ks * 32 + (lane >> 4) * 8;
  bf16x8 v;
#pragma unroll
  for (int e = 0; e < 8; ++e) v[e] = (bf16)src[(kb + e) * 64 + n];
  *reinterpret_cast<bf16x8*>(ws + mat * 4096 + ((ks * 4 + nt) * 64 + lane) * 8) = v;
}

// inst mapping: 0:U(u_movies,item | node user[uids])  1:M(m_querys,query | item[mids])
//               2:M(m_users,user | item[mids])        3:Q(q_movies,item | query[qids])

// ---- gat_all: r17 body VERBATIM; 1024-thread blocks (16 independent waves,
// no __syncthreads) to lift the command-processor block-dispatch bottleneck.
__global__ __launch_bounds__(1024) void gat_all(
    const int* __restrict__ uids, const int* __restrict__ qids,
    const int* __restrict__ mids, const int* __restrict__ u_movies,
    const int* __restrict__ m_querys, const int* __restrict__ m_users,
    const int* __restrict__ q_movies, const float* __restrict__ user_t,
    const float* __restrict__ item_t, const float* __restrict__ query_t,
    const float* __restrict__ gatW, const float* __restrict__ gatB,
    const bf16* __restrict__ wfrag, float* __restrict__ agg, int B) {
  int ib = (blockIdx.x * 1024 + threadIdx.x) >> 6;
  int lane = threadIdx.x & 63;
  int inst = ib / B;
  int b = ib - inst * B;
  int c15 = lane & 15, g = lane >> 4;

  const int* idx; const float* nbt; const float* ndt; int ndid; int woff;
  if (inst == 0) { idx = u_movies; nbt = item_t; ndt = user_t; ndid = uids[b]; woff = 0; }
  else if (inst == 1) { idx = m_querys; nbt = query_t; ndt = item_t; ndid = mids[b]; woff = 1; }
  else if (inst == 2) { idx = m_users; nbt = user_t; ndt = item_t; ndid = mids[b]; woff = 1; }
  else { idx = q_movies; nbt = item_t; ndt = query_t; ndid = qids[b]; woff = 2; }
  const float* Wt = gatW + (size_t)woff * 4 * 4096;
  const float* bt = gatB + woff * 256;
  const bf16* frk = wfrag + woff * 8192;        // K frags
  const bf16* frv = wfrag + woff * 8192 + 4096; // V frags

  // node row (one 256B gather per wave)
  float nd = ndt[(size_t)ndid * 64 + lane];

  // A fragments for all 4 m-tiles (rows 50..63 -> id 0 = zero row)
  bf16x8 af0[4], af1[4];
#pragma unroll
  for (int m = 0; m < 4; ++m) {
    int arow = m * 16 + c15;
    int id = (arow < S_NB) ? idx[b * S_NB + arow] : 0;
    const float* rowp = nbt + (size_t)id * 64;
    float4 f0 = *reinterpret_cast<const float4*>(rowp + g * 8);
    float4 f1 = *reinterpret_cast<const float4*>(rowp + g * 8 + 4);
    float4 f2 = *reinterpret_cast<const float4*>(rowp + 32 + g * 8);
    float4 f3 = *reinterpret_cast<const float4*>(rowp + 32 + g * 8 + 4);
    af0[m][0] = (bf16)f0.x; af0[m][1] = (bf16)f0.y; af0[m][2] = (bf16)f0.z; af0[m][3] = (bf16)f0.w;
    af0[m][4] = (bf16)f1.x; af0[m][5] = (bf16)f1.y; af0[m][6] = (bf16)f1.z; af0[m][7] = (bf16)f1.w;
    af1[m][0] = (bf16)f2.x; af1[m][1] = (bf16)f2.y; af1[m][2] = (bf16)f2.z; af1[m][3] = (bf16)f2.w;
    af1[m][4] = (bf16)f3.x; af1[m][5] = (bf16)f3.y; af1[m][6] = (bf16)f3.z; af1[m][7] = (bf16)f3.w;
  }

  // qp[col=lane] = relu(node @ W0 + b0), node broadcast via shuffle
  float qv_own;
  {
    float q0 = 0.f, q1 = 0.f, q2 = 0.f, q3 = 0.f;
#pragma unroll 4
    for (int k = 0; k < 64; k += 4) {
      q0 += __shfl(nd, k, 64) * Wt[k * 64 + lane];
      q1 += __shfl(nd, k + 1, 64) * Wt[(k + 1) * 64 + lane];
      q2 += __shfl(nd, k + 2, 64) * Wt[(k + 2) * 64 + lane];
      q3 += __shfl(nd, k + 3, 64) * Wt[(k + 3) * 64 + lane];
    }
    qv_own = fmaxf((((q0 + q1) + q2) + q3) + bt[lane], 0.f);
  }

  // K phase: scores s[m][e] (row = m*16 + g*4 + e, summed over nt cols)
  float s[4][4];
#pragma unroll
  for (int m = 0; m < 4; ++m)
#pragma unroll
    for (int e = 0; e < 4; ++e) s[m][e] = 0.f;
#pragma unroll
  for (int nt = 0; nt < 4; ++nt) {
    bf16x8 bk0 = *reinterpret_cast<const bf16x8*>(frk + ((0 * 4 + nt) * 64 + lane) * 8);
    bf16x8 bk1 = *reinterpret_cast<const bf16x8*>(frk + ((1 * 4 + nt) * 64 + lane) * 8);
    float kb = bt[64 + nt * 16 + c15];
    float qpv = __shfl(qv_own, nt * 16 + c15, 64);
#pragma unroll
    for (int m = 0; m < 4; ++m) {
      f32x4 acc = {0.f, 0.f, 0.f, 0.f};
      acc = __builtin_amdgcn_mfma_f32_16x16x32_bf16(af0[m], bk0, acc, 0, 0, 0);
      acc = __builtin_amdgcn_mfma_f32_16x16x32_bf16(af1[m], bk1, acc, 0, 0, 0);
#pragma unroll
      for (int e = 0; e < 4; ++e) s[m][e] += fmaxf(acc[e] + kb, 0.f) * qpv;
    }
  }
#pragma unroll
  for (int msk = 1; msk < 16; msk <<= 1)
#pragma unroll
    for (int m = 0; m < 4; ++m)
#pragma unroll
      for (int e = 0; e < 4; ++e) s[m][e] += __shfl_xor(s[m][e], msk, 64);

  // transpose to per-lane score: lane wants row == lane
  int m_l = lane >> 4, e_l = lane & 3, gg = (lane & 15) >> 2;
  float sv = -1e30f;
#pragma unroll
  for (int m = 0; m < 4; ++m)
#pragma unroll
    for (int e = 0; e < 4; ++e) {
      float v = __shfl(s[m][e], gg * 16, 64);
      sv = (m_l == m && e_l == e) ? v : sv;
    }

  // softmax over 50 (scale 1/8 folded into exp), in-wave
  float svm = (lane < S_NB) ? sv : -1e30f;
  float mx = svm;
#pragma unroll
  for (int msk = 1; msk < 64; msk <<= 1) mx = fmaxf(mx, __shfl_xor(mx, msk, 64));
  float ev = (lane < S_NB) ? __expf((svm - mx) * 0.125f) : 0.f;
  float den = ev;
#pragma unroll
  for (int msk = 1; msk < 64; msk <<= 1) den += __shfl_xor(den, msk, 64);
  float pv = ev / den;

  // prob weights for PV: pw[m][e] = prob of row m*16 + g*4 + e
  float pwv[4][4];
#pragma unroll
  for (int m = 0; m < 4; ++m)
#pragma unroll
    for (int e = 0; e < 4; ++e) pwv[m][e] = __shfl(pv, m * 16 + g * 4 + e, 64);

  // V phase: PV accumulate (A-frags reused from registers)
  float yacc[4] = {0.f, 0.f, 0.f, 0.f};
#pragma unroll
  for (int nt = 0; nt < 4; ++nt) {
    bf16x8 bv0 = *reinterpret_cast<const bf16x8*>(frv + ((0 * 4 + nt) * 64 + lane) * 8);
    bf16x8 bv1 = *reinterpret_cast<const bf16x8*>(frv + ((1 * 4 + nt) * 64 + lane) * 8);
    float vb = bt[128 + nt * 16 + c15];
#pragma unroll
    for (int m = 0; m < 4; ++m) {
      f32x4 acc = {0.f, 0.f, 0.f, 0.f};
      acc = __builtin_amdgcn_mfma_f32_16x16x32_bf16(af0[m], bv0, acc, 0, 0, 0);
      acc = __builtin_amdgcn_mfma_f32_16x16x32_bf16(af1[m], bv1, acc, 0, 0, 0);
      yacc[nt] += pwv[m][0] * fmaxf(acc[0] + vb, 0.f) +
                  pwv[m][1] * fmaxf(acc[1] + vb, 0.f) +
                  pwv[m][2] * fmaxf(acc[2] + vb, 0.f) +
                  pwv[m][3] * fmaxf(acc[3] + vb, 0.f);
    }
  }
#pragma unroll
  for (int nt = 0; nt < 4; ++nt) {
    yacc[nt] += __shfl_xor(yacc[nt], 16, 64);
    yacc[nt] += __shfl_xor(yacc[nt], 32, 64);
  }
  // after xor 16/32, lane l holds yacc[nt] = y[nt*16 + (l&15)] for every l.

  // agg = relu(y @ W3 + b3), col = lane (same 4-acc order as r17)
  {
    const float* W3 = Wt + 3 * 4096;
    float a0 = 0.f, a1 = 0.f, a2 = 0.f, a3 = 0.f;
#pragma unroll
    for (int k = 0; k < 64; k += 4) {
      a0 += __shfl(yacc[(k + 0) >> 4], (k + 0) & 15, 64) * W3[(k + 0) * 64 + lane];
      a1 += __shfl(yacc[(k + 1) >> 4], (k + 1) & 15, 64) * W3[(k + 1) * 64 + lane];
      a2 += __shfl(yacc[(k + 2) >> 4], (k + 2) & 15, 64) * W3[(k + 2) * 64 + lane];
      a3 += __shfl(yacc[(k + 3) >> 4], (k + 3) & 15, 64) * W3[(k + 3) * 64 + lane];
    }
    agg[(size_t)ib * 64 + lane] =
        fmaxf((((a0 + a1) + a2) + a3) + gatB[woff * 256 + 192 + lane], 0.f);
  }
}

// ---- k_sem: r17 body VERBATIM; 512-thread blocks (8 independent waves). ----
__global__ __launch_bounds__(512) void k_sem(
    const int* __restrict__ uids, const int* __restrict__ qids,
    const int* __restrict__ mids, const float* __restrict__ user_t,
    const float* __restrict__ item_t, const float* __restrict__ query_t,
    const float* __restrict__ semW, const float* __restrict__ semB,
    const float* __restrict__ agg, float* __restrict__ out, int B) {
  int w = (blockIdx.x * 512 + threadIdx.x) >> 6;
  int lane = threadIdx.x & 63;
  int t = w / B;
  int b = w - t * B;

  float nd, k1v, k2v;
  int ns;
  if (t == 0) {
    nd = user_t[(size_t)uids[b] * 64 + lane];
    k1v = agg[(size_t)(0 * B + b) * 64 + lane];
    k2v = k1v; ns = 2;
  } else if (t == 1) {
    nd = item_t[(size_t)mids[b] * 64 + lane];
    k1v = agg[(size_t)(1 * B + b) * 64 + lane];
    k2v = agg[(size_t)(2 * B + b) * 64 + lane];
    ns = 3;
  } else {
    nd = query_t[(size_t)qids[b] * 64 + lane];
    k1v = agg[(size_t)(3 * B + b) * 64 + lane];
    k2v = k1v; ns = 2;
  }
  const float* Ws = semW + (size_t)t * 4 * 4096;
  const float* bs = semB + t * 256;

  // qs = relu(node @ W0 + b0), col = lane
  float q0 = 0.f, q1 = 0.f;
#pragma unroll 4
  for (int k = 0; k < 64; k += 2) {
    q0 += __shfl(nd, k, 64) * Ws[k * 64 + lane];
    q1 += __shfl(nd, k + 1, 64) * Ws[(k + 1) * 64 + lane];
  }
  float qs = fmaxf(q0 + q1 + bs[lane], 0.f);

  // kp/vp rows for keys {node, k1, k2}
  const float* W1 = Ws + 4096;
  const float* W2 = Ws + 2 * 4096;
  float kp0 = 0.f, kp1 = 0.f, kp2 = 0.f, vp0 = 0.f, vp1 = 0.f, vp2 = 0.f;
#pragma unroll 2
  for (int k = 0; k < 64; ++k) {
    float w1 = W1[k * 64 + lane];
    float w2 = W2[k * 64 + lane];
    float nk = __shfl(nd, k, 64);
    float a1k = __shfl(k1v, k, 64);
    float a2k = __shfl(k2v, k, 64);
    kp0 += nk * w1; kp1 += a1k * w1; kp2 += a2k * w1;
    vp0 += nk * w2; vp1 += a1k * w2; vp2 += a2k * w2;
  }
  float bk = bs[64 + lane], bv = bs[128 + lane];
  kp0 = fmaxf(kp0 + bk, 0.f); kp1 = fmaxf(kp1 + bk, 0.f); kp2 = fmaxf(kp2 + bk, 0.f);
  vp0 = fmaxf(vp0 + bv, 0.f); vp1 = fmaxf(vp1 + bv, 0.f); vp2 = fmaxf(vp2 + bv, 0.f);

  // scores = dot(qs, kp_r)/8 via xor-tree
  float s0 = qs * kp0, s1 = qs * kp1, s2 = qs * kp2;
#pragma unroll
  for (int msk = 1; msk < 64; msk <<= 1) {
    s0 += __shfl_xor(s0, msk, 64);
    s1 += __shfl_xor(s1, msk, 64);
    s2 += __shfl_xor(s2, msk, 64);
  }
  s0 *= 0.125f; s1 *= 0.125f; s2 *= 0.125f;
  float mx = fmaxf(s0, s1);
  if (ns > 2) mx = fmaxf(mx, s2);
  float e0 = __expf(s0 - mx);
  float e1 = __expf(s1 - mx);
  float e2 = (ns > 2) ? __expf(s2 - mx) : 0.f;
  float rd = 1.f / (e0 + e1 + e2);
  float yv = (e0 * vp0 + e1 * vp1 + e2 * vp2) * rd;

  // out = relu(y @ W3 + b3)
  const float* W3 = Ws + 3 * 4096;
  float o0 = 0.f, o1 = 0.f;
#pragma unroll 4
  for (int k = 0; k < 64; k += 2) {
    o0 += __shfl(yv, k, 64) * W3[k * 64 + lane];
    o1 += __shfl(yv, k + 1, 64) * W3[(k + 1) * 64 + lane];
  }
  out[(size_t)b * 192 + t * 64 + lane] = fmaxf(o0 + o1 + bs[192 + lane], 0.f);
}

extern "C" void kernel_launch(void* const* d_in, const int* in_sizes, int n_in,
                              void* d_out, int out_size, void* d_ws, size_t ws_size,
                              hipStream_t stream) {
  const int* uids = (const int*)d_in[0];
  const int* qids = (const int*)d_in[1];
  const int* mids = (const int*)d_in[2];
  const int* u_movies = (const int*)d_in[3];
  const int* m_querys = (const int*)d_in[4];
  const int* m_users = (const int*)d_in[5];
  const int* q_movies = (const int*)d_in[6];
  const float* user_t = (const float*)d_in[7];
  const float* item_t = (const float*)d_in[8];
  const float* query_t = (const float*)d_in[9];
  const float* gatW = (const float*)d_in[10];
  const float* gatB = (const float*)d_in[11];
  const float* semW = (const float*)d_in[12];
  const float* semB = (const float*)d_in[13];
  float* out = (float*)d_out;

  int B = in_sizes[0];
  bf16* wfrag = (bf16*)d_ws;
  float* wsf = (float*)d_ws;
  float* agg = wsf + 16384;  // 4*B*64 floats

  shuffle_w<<<12, 256, 0, stream>>>(gatW, wfrag);
  // 4*B waves / 16 waves-per-block = B/4 blocks
  gat_all<<<B / 4, 1024, 0, stream>>>(uids, qids, mids, u_movies, m_querys,
                                      m_users, q_movies, user_t, item_t,
                                      query_t, gatW, gatB, wfrag, agg, B);
  // 3*B waves / 8 waves-per-block = 3*B/8 blocks
  k_sem<<<3 * B / 8, 512, 0, stream>>>(uids, qids, mids, user_t, item_t,
                                       query_t, semW, semB, agg, out, B);
}

// Round 23
// 470.490 us; speedup vs baseline: 1.1405x; 1.1194x over previous
//
#include <hip/hip_runtime.h>

typedef __bf16 bf16;
typedef __bf16 bf16x8 __attribute__((ext_vector_type(8)));
typedef float f32x4 __attribute__((ext_vector_type(4)));

#define S_NB 50

// ---------------- weight pre-shuffle: f32 -> bf16 MFMA B-fragment layout ----
__global__ __launch_bounds__(256) void shuffle_w(const float* __restrict__ gatW,
                                                 bf16* __restrict__ ws) {
  int tid = blockIdx.x * 256 + threadIdx.x;
  if (tid >= 6 * 512) return;
  int mat = tid >> 9;
  int rem = tid & 511;
  int ks = rem >> 8;
  int nt = (rem >> 6) & 3;
  int lane = rem & 63;
  int t = mat >> 1, p = (mat & 1) + 1;
  const float* src = gatW + (size_t)(t * 4 + p) * 4096;
  int n = nt * 16 + (lane & 15);
  int kb = ks * 32 + (lane >> 4) * 8;
  bf16x8 v;
#pragma unroll
  for (int e = 0; e < 8; ++e) v[e] = (bf16)src[(kb + e) * 64 + n];
  *reinterpret_cast<bf16x8*>(ws + mat * 4096 + ((ks * 4 + nt) * 64 + lane) * 8) = v;
}

// inst mapping: 0:U(u_movies,item | node user[uids])  1:M(m_querys,query | item[mids])
//               2:M(m_users,user | item[mids])        3:Q(q_movies,item | query[qids])

// ---- gat_all: qp + scores + softmax + PV + agg, one wave per (inst, b). ----
__global__ __launch_bounds__(256) void gat_all(
    const int* __restrict__ uids, const int* __restrict__ qids,
    const int* __restrict__ mids, const int* __restrict__ u_movies,
    const int* __restrict__ m_querys, const int* __restrict__ m_users,
    const int* __restrict__ q_movies, const float* __restrict__ user_t,
    const float* __restrict__ item_t, const float* __restrict__ query_t,
    const float* __restrict__ gatW, const float* __restrict__ gatB,
    const bf16* __restrict__ wfrag, float* __restrict__ agg, int B) {
  int ib = (blockIdx.x * 256 + threadIdx.x) >> 6;
  int lane = threadIdx.x & 63;
  int inst = ib / B;
  int b = ib - inst * B;
  int c15 = lane & 15, g = lane >> 4;

  const int* idx; const float* nbt; const float* ndt; int ndid; int woff;
  if (inst == 0) { idx = u_movies; nbt = item_t; ndt = user_t; ndid = uids[b]; woff = 0; }
  else if (inst == 1) { idx = m_querys; nbt = query_t; ndt = item_t; ndid = mids[b]; woff = 1; }
  else if (inst == 2) { idx = m_users; nbt = user_t; ndt = item_t; ndid = mids[b]; woff = 1; }
  else { idx = q_movies; nbt = item_t; ndt = query_t; ndid = qids[b]; woff = 2; }
  const float* Wt = gatW + (size_t)woff * 4 * 4096;
  const float* bt = gatB + woff * 256;
  const bf16* frk = wfrag + woff * 8192;        // K frags
  const bf16* frv = wfrag + woff * 8192 + 4096; // V frags

  // node row (one 256B gather per wave)
  float nd = ndt[(size_t)ndid * 64 + lane];

  // A fragments for all 4 m-tiles (rows 50..63 -> id 0 = zero row)
  bf16x8 af0[4], af1[4];
#pragma unroll
  for (int m = 0; m < 4; ++m) {
    int arow = m * 16 + c15;
    int id = (arow < S_NB) ? idx[b * S_NB + arow] : 0;
    const float* rowp = nbt + (size_t)id * 64;
    float4 f0 = *reinterpret_cast<const float4*>(rowp + g * 8);
    float4 f1 = *reinterpret_cast<const float4*>(rowp + g * 8 + 4);
    float4 f2 = *reinterpret_cast<const float4*>(rowp + 32 + g * 8);
    float4 f3 = *reinterpret_cast<const float4*>(rowp + 32 + g * 8 + 4);
    af0[m][0] = (bf16)f0.x; af0[m][1] = (bf16)f0.y; af0[m][2] = (bf16)f0.z; af0[m][3] = (bf16)f0.w;
    af0[m][4] = (bf16)f1.x; af0[m][5] = (bf16)f1.y; af0[m][6] = (bf16)f1.z; af0[m][7] = (bf16)f1.w;
    af1[m][0] = (bf16)f2.x; af1[m][1] = (bf16)f2.y; af1[m][2] = (bf16)f2.z; af1[m][3] = (bf16)f2.w;
    af1[m][4] = (bf16)f3.x; af1[m][5] = (bf16)f3.y; af1[m][6] = (bf16)f3.z; af1[m][7] = (bf16)f3.w;
  }

  // qp[col=lane] = relu(node @ W0 + b0), node broadcast via shuffle
  float qv_own;
  {
    float q0 = 0.f, q1 = 0.f, q2 = 0.f, q3 = 0.f;
#pragma unroll 4
    for (int k = 0; k < 64; k += 4) {
      q0 += __shfl(nd, k, 64) * Wt[k * 64 + lane];
      q1 += __shfl(nd, k + 1, 64) * Wt[(k + 1) * 64 + lane];
      q2 += __shfl(nd, k + 2, 64) * Wt[(k + 2) * 64 + lane];
      q3 += __shfl(nd, k + 3, 64) * Wt[(k + 3) * 64 + lane];
    }
    qv_own = fmaxf((((q0 + q1) + q2) + q3) + bt[lane], 0.f);
  }

  // K phase: scores s[m][e] (row = m*16 + g*4 + e, summed over nt cols)
  float s[4][4];
#pragma unroll
  for (int m = 0; m < 4; ++m)
#pragma unroll
    for (int e = 0; e < 4; ++e) s[m][e] = 0.f;
#pragma unroll
  for (int nt = 0; nt < 4; ++nt) {
    bf16x8 bk0 = *reinterpret_cast<const bf16x8*>(frk + ((0 * 4 + nt) * 64 + lane) * 8);
    bf16x8 bk1 = *reinterpret_cast<const bf16x8*>(frk + ((1 * 4 + nt) * 64 + lane) * 8);
    float kb = bt[64 + nt * 16 + c15];
    float qpv = __shfl(qv_own, nt * 16 + c15, 64);
#pragma unroll
    for (int m = 0; m < 4; ++m) {
      f32x4 acc = {0.f, 0.f, 0.f, 0.f};
      acc = __builtin_amdgcn_mfma_f32_16x16x32_bf16(af0[m], bk0, acc, 0, 0, 0);
      acc = __builtin_amdgcn_mfma_f32_16x16x32_bf16(af1[m], bk1, acc, 0, 0, 0);
#pragma unroll
      for (int e = 0; e < 4; ++e) s[m][e] += fmaxf(acc[e] + kb, 0.f) * qpv;
    }
  }
#pragma unroll
  for (int msk = 1; msk < 16; msk <<= 1)
#pragma unroll
    for (int m = 0; m < 4; ++m)
#pragma unroll
      for (int e = 0; e < 4; ++e) s[m][e] += __shfl_xor(s[m][e], msk, 64);

  // transpose to per-lane score: lane wants row == lane
  int m_l = lane >> 4, e_l = lane & 3, gg = (lane & 15) >> 2;
  float sv = -1e30f;
#pragma unroll
  for (int m = 0; m < 4; ++m)
#pragma unroll
    for (int e = 0; e < 4; ++e) {
      float v = __shfl(s[m][e], gg * 16, 64);
      sv = (m_l == m && e_l == e) ? v : sv;
    }

  // softmax over 50 (scale 1/8 folded into exp), in-wave
  float svm = (lane < S_NB) ? sv : -1e30f;
  float mx = svm;
#pragma unroll
  for (int msk = 1; msk < 64; msk <<= 1) mx = fmaxf(mx, __shfl_xor(mx, msk, 64));
  float ev = (lane < S_NB) ? __expf((svm - mx) * 0.125f) : 0.f;
  float den = ev;
#pragma unroll
  for (int msk = 1; msk < 64; msk <<= 1) den += __shfl_xor(den, msk, 64);
  float pv = ev / den;

  // prob weights for PV: pw[m][e] = prob of row m*16 + g*4 + e
  float pwv[4][4];
#pragma unroll
  for (int m = 0; m < 4; ++m)
#pragma unroll
    for (int e = 0; e < 4; ++e) pwv[m][e] = __shfl(pv, m * 16 + g * 4 + e, 64);

  // V phase: PV accumulate (A-frags reused from registers)
  float yacc[4] = {0.f, 0.f, 0.f, 0.f};
#pragma unroll
  for (int nt = 0; nt < 4; ++nt) {
    bf16x8 bv0 = *reinterpret_cast<const bf16x8*>(frv + ((0 * 4 + nt) * 64 + lane) * 8);
    bf16x8 bv1 = *reinterpret_cast<const bf16x8*>(frv + ((1 * 4 + nt) * 64 + lane) * 8);
    float vb = bt[128 + nt * 16 + c15];
#pragma unroll
    for (int m = 0; m < 4; ++m) {
      f32x4 acc = {0.f, 0.f, 0.f, 0.f};
      acc = __builtin_amdgcn_mfma_f32_16x16x32_bf16(af0[m], bv0, acc, 0, 0, 0);
      acc = __builtin_amdgcn_mfma_f32_16x16x32_bf16(af1[m], bv1, acc, 0, 0, 0);
      yacc[nt] += pwv[m][0] * fmaxf(acc[0] + vb, 0.f) +
                  pwv[m][1] * fmaxf(acc[1] + vb, 0.f) +
                  pwv[m][2] * fmaxf(acc[2] + vb, 0.f) +
                  pwv[m][3] * fmaxf(acc[3] + vb, 0.f);
    }
  }
#pragma unroll
  for (int nt = 0; nt < 4; ++nt) {
    yacc[nt] += __shfl_xor(yacc[nt], 16, 64);
    yacc[nt] += __shfl_xor(yacc[nt], 32, 64);
  }
  // after xor 16/32, lane l holds yacc[nt] = y[nt*16 + (l&15)] for every l.

  // agg = relu(y @ W3 + b3), col = lane
  {
    const float* W3 = Wt + 3 * 4096;
    float a0 = 0.f, a1 = 0.f, a2 = 0.f, a3 = 0.f;
#pragma unroll
    for (int k = 0; k < 64; k += 4) {
      a0 += __shfl(yacc[(k + 0) >> 4], (k + 0) & 15, 64) * W3[(k + 0) * 64 + lane];
      a1 += __shfl(yacc[(k + 1) >> 4], (k + 1) & 15, 64) * W3[(k + 1) * 64 + lane];
      a2 += __shfl(yacc[(k + 2) >> 4], (k + 2) & 15, 64) * W3[(k + 2) * 64 + lane];
      a3 += __shfl(yacc[(k + 3) >> 4], (k + 3) & 15, 64) * W3[(k + 3) * 64 + lane];
    }
    agg[(size_t)ib * 64 + lane] =
        fmaxf((((a0 + a1) + a2) + a3) + gatB[woff * 256 + 192 + lane], 0.f);
  }
}

// ---- k_sem: semantic attention. one wave per (tower, b). -------------------
__global__ __launch_bounds__(256) void k_sem(
    const int* __restrict__ uids, const int* __restrict__ qids,
    const int* __restrict__ mids, const float* __restrict__ user_t,
    const float* __restrict__ item_t, const float* __restrict__ query_t,
    const float* __restrict__ semW, const float* __restrict__ semB,
    const float* __restrict__ agg, float* __restrict__ out, int B) {
  int w = (blockIdx.x * 256 + threadIdx.x) >> 6;
  int lane = threadIdx.x & 63;
  int t = w / B;
  int b = w - t * B;

  float nd, k1v, k2v;
  int ns;
  if (t == 0) {
    nd = user_t[(size_t)uids[b] * 64 + lane];
    k1v = agg[(size_t)(0 * B + b) * 64 + lane];
    k2v = k1v; ns = 2;
  } else if (t == 1) {
    nd = item_t[(size_t)mids[b] * 64 + lane];
    k1v = agg[(size_t)(1 * B + b) * 64 + lane];
    k2v = agg[(size_t)(2 * B + b) * 64 + lane];
    ns = 3;
  } else {
    nd = query_t[(size_t)qids[b] * 64 + lane];
    k1v = agg[(size_t)(3 * B + b) * 64 + lane];
    k2v = k1v; ns = 2;
  }
  const float* Ws = semW + (size_t)t * 4 * 4096;
  const float* bs = semB + t * 256;

  // qs = relu(node @ W0 + b0), col = lane
  float q0 = 0.f, q1 = 0.f;
#pragma unroll 4
  for (int k = 0; k < 64; k += 2) {
    q0 += __shfl(nd, k, 64) * Ws[k * 64 + lane];
    q1 += __shfl(nd, k + 1, 64) * Ws[(k + 1) * 64 + lane];
  }
  float qs = fmaxf(q0 + q1 + bs[lane], 0.f);

  // kp/vp rows for keys {node, k1, k2}
  const float* W1 = Ws + 4096;
  const float* W2 = Ws + 2 * 4096;
  float kp0 = 0.f, kp1 = 0.f, kp2 = 0.f, vp0 = 0.f, vp1 = 0.f, vp2 = 0.f;
#pragma unroll 2
  for (int k = 0; k < 64; ++k) {
    float w1 = W1[k * 64 + lane];
    float w2 = W2[k * 64 + lane];
    float nk = __shfl(nd, k, 64);
    float a1k = __shfl(k1v, k, 64);
    float a2k = __shfl(k2v, k, 64);
    kp0 += nk * w1; kp1 += a1k * w1; kp2 += a2k * w1;
    vp0 += nk * w2; vp1 += a1k * w2; vp2 += a2k * w2;
  }
  float bk = bs[64 + lane], bv = bs[128 + lane];
  kp0 = fmaxf(kp0 + bk, 0.f); kp1 = fmaxf(kp1 + bk, 0.f); kp2 = fmaxf(kp2 + bk, 0.f);
  vp0 = fmaxf(vp0 + bv, 0.f); vp1 = fmaxf(vp1 + bv, 0.f); vp2 = fmaxf(vp2 + bv, 0.f);

  // scores = dot(qs, kp_r)/8 via xor-tree
  float s0 = qs * kp0, s1 = qs * kp1, s2 = qs * kp2;
#pragma unroll
  for (int msk = 1; msk < 64; msk <<= 1) {
    s0 += __shfl_xor(s0, msk, 64);
    s1 += __shfl_xor(s1, msk, 64);
    s2 += __shfl_xor(s2, msk, 64);
  }
  s0 *= 0.125f; s1 *= 0.125f; s2 *= 0.125f;
  float mx = fmaxf(s0, s1);
  if (ns > 2) mx = fmaxf(mx, s2);
  float e0 = __expf(s0 - mx);
  float e1 = __expf(s1 - mx);
  float e2 = (ns > 2) ? __expf(s2 - mx) : 0.f;
  float rd = 1.f / (e0 + e1 + e2);
  float yv = (e0 * vp0 + e1 * vp1 + e2 * vp2) * rd;

  // out = relu(y @ W3 + b3)
  const float* W3 = Ws + 3 * 4096;
  float o0 = 0.f, o1 = 0.f;
#pragma unroll 4
  for (int k = 0; k < 64; k += 2) {
    o0 += __shfl(yv, k, 64) * W3[k * 64 + lane];
    o1 += __shfl(yv, k + 1, 64) * W3[(k + 1) * 64 + lane];
  }
  out[(size_t)b * 192 + t * 64 + lane] = fmaxf(o0 + o1 + bs[192 + lane], 0.f);
}

extern "C" void kernel_launch(void* const* d_in, const int* in_sizes, int n_in,
                              void* d_out, int out_size, void* d_ws, size_t ws_size,
                              hipStream_t stream) {
  const int* uids = (const int*)d_in[0];
  const int* qids = (const int*)d_in[1];
  const int* mids = (const int*)d_in[2];
  const int* u_movies = (const int*)d_in[3];
  const int* m_querys = (const int*)d_in[4];
  const int* m_users = (const int*)d_in[5];
  const int* q_movies = (const int*)d_in[6];
  const float* user_t = (const float*)d_in[7];
  const float* item_t = (const float*)d_in[8];
  const float* query_t = (const float*)d_in[9];
  const float* gatW = (const float*)d_in[10];
  const float* gatB = (const float*)d_in[11];
  const float* semW = (const float*)d_in[12];
  const float* semB = (const float*)d_in[13];
  float* out = (float*)d_out;

  int B = in_sizes[0];
  bf16* wfrag = (bf16*)d_ws;
  float* wsf = (float*)d_ws;
  float* agg = wsf + 16384;  // 4*B*64 floats

  shuffle_w<<<12, 256, 0, stream>>>(gatW, wfrag);
  gat_all<<<B, 256, 0, stream>>>(uids, qids, mids, u_movies, m_querys,
                                 m_users, q_movies, user_t, item_t, query_t,
                                 gatW, gatB, wfrag, agg, B);
  k_sem<<<3 * B / 4, 256, 0, stream>>>(uids, qids, mids, user_t, item_t,
                                       query_t, semW, semB, agg, out, B);
}